// Round 3
// baseline (1138.794 us; speedup 1.0000x reference)
//
#include <hip/hip_runtime.h>
#include <cstddef>

typedef _Float16 h2 __attribute__((ext_vector_type(2)));
typedef unsigned int uint32;

constexpr int S = 64, A = 16, MSG = 32, C = 4, CH = 73;

// packed f16x2 weight arrays, element counts (u32)
constexpr int W1P_N = 40 * 64;  // [k2][j]  k2: pairs over 80 inputs, j: 64 outs
constexpr int WAP_N = 37 * 32;  // [k2][j]  k2: pairs over 73 (+pad), j: 32 outs
constexpr int W2P_N = 64 * 48;  // [jb][k2] jb: 64 outs, k2: pairs over 96 ins
constexpr int W3P_N = 32 * 32;  // [jb2][j] jb2: pairs over 64 ins, j: 32 outs
constexpr int W1P_OFF = 0;
constexpr int WAP_OFF = W1P_OFF + W1P_N;
constexpr int W2P_OFF = WAP_OFF + WAP_N;
constexpr int W3P_OFF = W2P_OFF + W2P_N;
constexpr int WTOT = W3P_OFF + W3P_N;  // 7840 u32 = 31360 B

__device__ __forceinline__ uint32 packh(float a, float b) {
  union { _Float16 h[2]; uint32 u; } v;
  v.h[0] = (_Float16)a;  // RNE
  v.h[1] = (_Float16)b;
  return v.u;
}
__device__ __forceinline__ h2 ash2(uint32 u) {
  union { uint32 u; h2 h; } v; v.u = u; return v.h;
}
__device__ __forceinline__ h2 pk(float a, float b) {
  auto r = __builtin_amdgcn_cvt_pkrtz(a, b);  // __fp16x2
  union { decltype(r) f; h2 h; } v; v.f = r; return v.h;
}
__device__ __forceinline__ float fdot2(h2 a, h2 b, float c) {
  return __builtin_amdgcn_fdot2(a, b, c, false);
}
__device__ __forceinline__ float fast_tanh(float v) {
  v = fminf(15.f, fmaxf(-15.f, v));
  float t = __expf(2.f * v);
  return (t - 1.f) * __builtin_amdgcn_rcpf(t + 1.f);
}

__global__ void prep_pack(const float* __restrict__ W1, const float* __restrict__ Wa,
                          const float* __restrict__ W2, const float* __restrict__ W3,
                          uint32* __restrict__ ws) {
  int t = blockIdx.x * 256 + threadIdx.x;
  if (t < W1P_N) {  // W1 is [64][80]
    int k2 = t >> 6, j = t & 63;
    ws[W1P_OFF + t] = packh(W1[j * 80 + 2 * k2], W1[j * 80 + 2 * k2 + 1]);
  }
  if (t < WAP_N) {  // Wa is [32][73]
    int k2 = t >> 5, j = t & 31;
    float a = Wa[j * 73 + 2 * k2];
    float b = (2 * k2 + 1 < 73) ? Wa[j * 73 + 2 * k2 + 1] : 0.f;
    ws[WAP_OFF + t] = packh(a, b);
  }
  if (t < W2P_N) {  // W2 is [64][96]
    int jb = t / 48, k2 = t % 48;
    ws[W2P_OFF + t] = packh(W2[jb * 96 + 2 * k2], W2[jb * 96 + 2 * k2 + 1]);
  }
  if (t < W3P_N) {  // W3 is [32][64]
    int j2 = t >> 5, j = t & 31;
    ws[W3P_OFF + t] = packh(W3[j * 64 + 2 * j2], W3[j * 64 + 2 * j2 + 1]);
  }
}

__launch_bounds__(256, 4)
__global__ void critic_fused_kernel(
    const float* __restrict__ x, const float* __restrict__ u,
    const float* __restrict__ cs, const float* __restrict__ m,
    const float* __restrict__ b1, const float* __restrict__ b2,
    const float* __restrict__ b3, const float* __restrict__ ba,
    const uint32* __restrict__ wsp, float* __restrict__ out, int n) {
  __shared__ __attribute__((aligned(16))) uint32 wlds[WTOT];
  // cooperative weight stage: 7840 u32 = 1960 uint4
  {
    const uint4* src = reinterpret_cast<const uint4*>(wsp);
    uint4* dst = reinterpret_cast<uint4*>(wlds);
    for (int i = threadIdx.x; i < WTOT / 4; i += 256) dst[i] = src[i];
  }
  __syncthreads();

  const int b = blockIdx.x * blockDim.x + threadIdx.x;
  if (b >= n) return;

  // ---------------- Phase A: attention over children -> magg[32] -------------
  float num[MSG], den[MSG];
#pragma unroll
  for (int j = 0; j < MSG; ++j) { num[j] = 0.f; den[j] = 0.f; }

  for (int c = 0; c < C; ++c) {
    const float* __restrict__ csrow = cs + ((size_t)b * C + c) * CH;
    float z[MSG];
#pragma unroll
    for (int j = 0; j < MSG; ++j) z[j] = ba[j];  // uniform -> s_load

    for (int t = 0; t < 36; ++t) {  // dynamic loop; uniform LDS base
      h2 p = pk(csrow[2 * t], csrow[2 * t + 1]);
      const int base = WAP_OFF + t * 32;
#pragma unroll
      for (int j = 0; j < MSG; ++j) z[j] = fdot2(p, ash2(wlds[base + j]), z[j]);
    }
    {  // remainder k=72 (weight pair padded with 0)
      h2 p = pk(csrow[72], 0.f);
      const int base = WAP_OFF + 36 * 32;
#pragma unroll
      for (int j = 0; j < MSG; ++j) z[j] = fdot2(p, ash2(wlds[base + j]), z[j]);
    }

    const float4* __restrict__ m4 =
        reinterpret_cast<const float4*>(m + (size_t)b * (C * MSG) + c * MSG);
#pragma unroll
    for (int j4 = 0; j4 < MSG / 4; ++j4) {
      float4 mv = m4[j4];
      float ma[4] = {mv.x, mv.y, mv.z, mv.w};
#pragma unroll
      for (int jj = 0; jj < 4; ++jj) {
        int j = j4 * 4 + jj;
        float e = __expf(z[j]);
        den[j] += e;
        num[j] = fmaf(ma[jj], e, num[j]);
      }
    }
  }

  // ---------------- Phase B: fc1 on cat(x,u) -> h1[64] -----------------------
  float h1[64];
#pragma unroll
  for (int j = 0; j < 64; ++j) h1[j] = b1[j];

  const float4* __restrict__ xrow = reinterpret_cast<const float4*>(x + (size_t)b * S);
  for (int k4 = 0; k4 < S / 4; ++k4) {  // dynamic, 16 iters
    float4 xv = xrow[k4];
    h2 p0 = pk(xv.x, xv.y), p1 = pk(xv.z, xv.w);
    const int b0 = W1P_OFF + (2 * k4) * 64;
    const int b1o = b0 + 64;
#pragma unroll
    for (int j = 0; j < 64; ++j) h1[j] = fdot2(p0, ash2(wlds[b0 + j]), h1[j]);
#pragma unroll
    for (int j = 0; j < 64; ++j) h1[j] = fdot2(p1, ash2(wlds[b1o + j]), h1[j]);
  }
  const float4* __restrict__ urow = reinterpret_cast<const float4*>(u + (size_t)b * A);
  for (int k4 = 0; k4 < A / 4; ++k4) {  // dynamic, 4 iters
    float4 uv = urow[k4];
    h2 p0 = pk(uv.x, uv.y), p1 = pk(uv.z, uv.w);
    const int b0 = W1P_OFF + (32 + 2 * k4) * 64;
    const int b1o = b0 + 64;
#pragma unroll
    for (int j = 0; j < 64; ++j) h1[j] = fdot2(p0, ash2(wlds[b0 + j]), h1[j]);
#pragma unroll
    for (int j = 0; j < 64; ++j) h1[j] = fdot2(p1, ash2(wlds[b1o + j]), h1[j]);
  }

  // ---------------- Phase C: L2-normalize h1; tanh -> packed xup[48] ---------
  float s0 = 0.f, s1 = 0.f, s2 = 0.f, s3 = 0.f;
#pragma unroll
  for (int j = 0; j < 64; j += 4) {
    s0 = fmaf(h1[j + 0], h1[j + 0], s0);
    s1 = fmaf(h1[j + 1], h1[j + 1], s1);
    s2 = fmaf(h1[j + 2], h1[j + 2], s2);
    s3 = fmaf(h1[j + 3], h1[j + 3], s3);
  }
  float rn = __builtin_amdgcn_rsqf(fmaxf((s0 + s1) + (s2 + s3), 1e-24f));

  h2 xup[48];
#pragma unroll
  for (int j2 = 0; j2 < 32; ++j2)
    xup[j2] = pk(fast_tanh(h1[2 * j2] * rn), fast_tanh(h1[2 * j2 + 1] * rn));
#pragma unroll
  for (int j2 = 0; j2 < 16; ++j2) {
    float ma = num[2 * j2] * __builtin_amdgcn_rcpf(den[2 * j2]);
    float mb = num[2 * j2 + 1] * __builtin_amdgcn_rcpf(den[2 * j2 + 1]);
    xup[32 + j2] = pk(fast_tanh(ma), fast_tanh(mb));
  }

  // ---------------- Phase D: fc2 (2 rows/iter) chained into fc3 --------------
  float o[MSG];
#pragma unroll
  for (int j = 0; j < MSG; ++j) o[j] = b3[j];

  for (int j2 = 0; j2 < 32; ++j2) {  // dynamic, 64 fc2 rows as 32 pairs
    const int ba0 = W2P_OFF + (2 * j2) * 48;
    const int ba1 = ba0 + 48;
    float a0 = b2[2 * j2], a1 = 0.f;
    float c0 = b2[2 * j2 + 1], c1 = 0.f;
#pragma unroll
    for (int k = 0; k < 48; k += 2) {
      a0 = fdot2(xup[k], ash2(wlds[ba0 + k]), a0);
      a1 = fdot2(xup[k + 1], ash2(wlds[ba0 + k + 1]), a1);
      c0 = fdot2(xup[k], ash2(wlds[ba1 + k]), c0);
      c1 = fdot2(xup[k + 1], ash2(wlds[ba1 + k + 1]), c1);
    }
    h2 hp = pk(fast_tanh(a0 + a1), fast_tanh(c0 + c1));
    const int b3o = W3P_OFF + j2 * 32;
#pragma unroll
    for (int j = 0; j < MSG; ++j) o[j] = fdot2(hp, ash2(wlds[b3o + j]), o[j]);
  }

  // ---------------- Phase E: final L2 norm + store ---------------------------
  float t0 = 0.f, t1 = 0.f, t2 = 0.f, t3 = 0.f;
#pragma unroll
  for (int j = 0; j < MSG; j += 4) {
    t0 = fmaf(o[j + 0], o[j + 0], t0);
    t1 = fmaf(o[j + 1], o[j + 1], t1);
    t2 = fmaf(o[j + 2], o[j + 2], t2);
    t3 = fmaf(o[j + 3], o[j + 3], t3);
  }
  float rn2 = __builtin_amdgcn_rsqf(fmaxf((t0 + t1) + (t2 + t3), 1e-24f));

  float4* __restrict__ orow = reinterpret_cast<float4*>(out + (size_t)b * MSG);
#pragma unroll
  for (int j4 = 0; j4 < MSG / 4; ++j4) {
    float4 ov;
    ov.x = o[j4 * 4 + 0] * rn2;
    ov.y = o[j4 * 4 + 1] * rn2;
    ov.z = o[j4 * 4 + 2] * rn2;
    ov.w = o[j4 * 4 + 3] * rn2;
    orow[j4] = ov;
  }
}

extern "C" void kernel_launch(void* const* d_in, const int* in_sizes, int n_in,
                              void* d_out, int out_size, void* d_ws, size_t ws_size,
                              hipStream_t stream) {
  const float* x  = (const float*)d_in[0];
  const float* u  = (const float*)d_in[1];
  const float* cs = (const float*)d_in[2];
  const float* m  = (const float*)d_in[3];
  const float* W1 = (const float*)d_in[4];
  const float* b1 = (const float*)d_in[5];
  const float* W2 = (const float*)d_in[6];
  const float* b2 = (const float*)d_in[7];
  const float* W3 = (const float*)d_in[8];
  const float* b3 = (const float*)d_in[9];
  const float* Wa = (const float*)d_in[10];
  const float* ba = (const float*)d_in[11];
  float* out = (float*)d_out;
  uint32* ws = (uint32*)d_ws;

  const int n = in_sizes[0] / S;  // batch rows

  hipLaunchKernelGGL(prep_pack, dim3(12), dim3(256), 0, stream, W1, Wa, W2, W3, ws);

  const int blocks = (n + 255) / 256;
  hipLaunchKernelGGL(critic_fused_kernel, dim3(blocks), dim3(256), 0, stream,
                     x, u, cs, m, b1, b2, b3, ba, ws, out, n);
}

// Round 4
// 540.730 us; speedup vs baseline: 2.1060x; 2.1060x over previous
//
#include <hip/hip_runtime.h>
#include <cstddef>

typedef _Float16 h2 __attribute__((ext_vector_type(2)));
typedef unsigned int uint32;

constexpr int S = 64, A = 16, MSG = 32, C = 4, CH = 73;

// packed f16x2 weight arrays, element counts (u32)
constexpr int W1P_N = 40 * 64;  // [k2][j]  k2: pairs over 80 inputs, j: 64 outs
constexpr int WAP_N = 37 * 32;  // [k2][j]  k2: pairs over 73 (+pad), j: 32 outs
constexpr int W2P_N = 64 * 48;  // [jb][k2] jb: 64 outs, k2: pairs over 96 ins
constexpr int W3P_N = 32 * 32;  // [j2][j]  j2: pairs over 64 ins, j: 32 outs
constexpr int W1P_OFF = 0;
constexpr int WAP_OFF = W1P_OFF + W1P_N;   // 2560
constexpr int W2P_OFF = WAP_OFF + WAP_N;   // 3744
constexpr int W3P_OFF = W2P_OFF + W2P_N;   // 6816
constexpr int WTOT = W3P_OFF + W3P_N;      // 7840 u32 = 31360 B

__device__ __forceinline__ uint32 packh(float a, float b) {
  union { _Float16 h[2]; uint32 u; } v;
  v.h[0] = (_Float16)a;  // RNE
  v.h[1] = (_Float16)b;
  return v.u;
}
__device__ __forceinline__ uint32 pku(float a, float b) {
  auto r = __builtin_amdgcn_cvt_pkrtz(a, b);
  union { decltype(r) f; uint32 u; } v; v.f = r; return v.u;
}
__device__ __forceinline__ float fd(uint32 a, uint32 b, float c) {
  union { uint32 u; h2 h; } xa, xb; xa.u = a; xb.u = b;
  return __builtin_amdgcn_fdot2(xa.h, xb.h, c, false);
}
__device__ __forceinline__ float fast_tanh(float v) {
  v = fminf(15.f, fmaxf(-15.f, v));
  float t = __expf(2.f * v);
  return (t - 1.f) * __builtin_amdgcn_rcpf(t + 1.f);
}

__global__ void prep_pack(const float* __restrict__ W1, const float* __restrict__ Wa,
                          const float* __restrict__ W2, const float* __restrict__ W3,
                          uint32* __restrict__ ws) {
  int t = blockIdx.x * 256 + threadIdx.x;
  if (t < W1P_N) {  // W1 is [64][80]
    int k2 = t >> 6, j = t & 63;
    ws[W1P_OFF + t] = packh(W1[j * 80 + 2 * k2], W1[j * 80 + 2 * k2 + 1]);
  }
  if (t < WAP_N) {  // Wa is [32][73]
    int k2 = t >> 5, j = t & 31;
    float a = Wa[j * 73 + 2 * k2];
    float b = (2 * k2 + 1 < 73) ? Wa[j * 73 + 2 * k2 + 1] : 0.f;
    ws[WAP_OFF + t] = packh(a, b);
  }
  if (t < W2P_N) {  // W2 is [64][96]
    int jb = t / 48, k2 = t % 48;
    ws[W2P_OFF + t] = packh(W2[jb * 96 + 2 * k2], W2[jb * 96 + 2 * k2 + 1]);
  }
  if (t < W3P_N) {  // W3 is [32][64]
    int j2 = t >> 5, j = t & 31;
    ws[W3P_OFF + t] = packh(W3[j * 64 + 2 * j2], W3[j * 64 + 2 * j2 + 1]);
  }
}

// z[0..31] += p · w[k2-row], weights read as 8 x ds_read_b128 (broadcast)
__device__ __forceinline__ void dot32(const uint32* __restrict__ w, uint32 p,
                                      float* __restrict__ z) {
#pragma unroll
  for (int q = 0; q < 8; ++q) {
    uint4 wv = *reinterpret_cast<const uint4*>(w + 4 * q);
    z[4 * q + 0] = fd(p, wv.x, z[4 * q + 0]);
    z[4 * q + 1] = fd(p, wv.y, z[4 * q + 1]);
    z[4 * q + 2] = fd(p, wv.z, z[4 * q + 2]);
    z[4 * q + 3] = fd(p, wv.w, z[4 * q + 3]);
  }
}
__device__ __forceinline__ void dot64(const uint32* __restrict__ w, uint32 p,
                                      float* __restrict__ h) {
#pragma unroll
  for (int q = 0; q < 16; ++q) {
    uint4 wv = *reinterpret_cast<const uint4*>(w + 4 * q);
    h[4 * q + 0] = fd(p, wv.x, h[4 * q + 0]);
    h[4 * q + 1] = fd(p, wv.y, h[4 * q + 1]);
    h[4 * q + 2] = fd(p, wv.z, h[4 * q + 2]);
    h[4 * q + 3] = fd(p, wv.w, h[4 * q + 3]);
  }
}

__launch_bounds__(256)
__global__ void critic_fused_kernel(
    const float* __restrict__ x, const float* __restrict__ u,
    const float* __restrict__ cs, const float* __restrict__ m,
    const float* __restrict__ b1, const float* __restrict__ b2,
    const float* __restrict__ b3, const float* __restrict__ ba,
    const uint32* __restrict__ wsp, float* __restrict__ out, int n) {
  __shared__ __attribute__((aligned(16))) uint32 wlds[WTOT];
  {
    const uint4* src = reinterpret_cast<const uint4*>(wsp);
    uint4* dst = reinterpret_cast<uint4*>(wlds);
    for (int i = threadIdx.x; i < WTOT / 4; i += 256) dst[i] = src[i];
  }
  __syncthreads();

  const int b = blockIdx.x * blockDim.x + threadIdx.x;
  if (b >= n) return;

  uint32 xup[48];  // packed fc2 input; [32:48] filled after phase A, [0:32] after B

  // ---------------- Phase A: attention over children -> xup[32:48] -----------
  {
    float num[MSG], den[MSG];
#pragma unroll
    for (int j = 0; j < MSG; ++j) { num[j] = 0.f; den[j] = 0.f; }

    for (int c = 0; c < C; ++c) {
      const float* __restrict__ csrow = cs + ((size_t)b * C + c) * CH;
      float z[MSG];
#pragma unroll
      for (int j = 0; j < MSG; ++j) z[j] = ba[j];  // uniform -> s_load

      for (int g = 0; g < 9; ++g) {  // dynamic; 8 streamed floats per iter
        float f0 = csrow[8 * g + 0], f1 = csrow[8 * g + 1];
        float f2 = csrow[8 * g + 2], f3 = csrow[8 * g + 3];
        float f4 = csrow[8 * g + 4], f5 = csrow[8 * g + 5];
        float f6 = csrow[8 * g + 6], f7 = csrow[8 * g + 7];
        uint32 p0 = pku(f0, f1), p1 = pku(f2, f3);
        uint32 p2 = pku(f4, f5), p3 = pku(f6, f7);
        const uint32* wb = &wlds[WAP_OFF + (4 * g) * 32];
        dot32(wb, p0, z);
        dot32(wb + 32, p1, z);
        dot32(wb + 64, p2, z);
        dot32(wb + 96, p3, z);
      }
      {  // remainder k = 72 (weight pair zero-padded)
        uint32 p = pku(csrow[72], 0.f);
        dot32(&wlds[WAP_OFF + 36 * 32], p, z);
      }

      const float* __restrict__ mrow = m + (size_t)b * (C * MSG) + c * MSG;
#pragma unroll
      for (int j4 = 0; j4 < MSG / 4; ++j4) {
        float4 mv = *reinterpret_cast<const float4*>(mrow + 4 * j4);
        float ma[4] = {mv.x, mv.y, mv.z, mv.w};
#pragma unroll
        for (int jj = 0; jj < 4; ++jj) {
          int j = j4 * 4 + jj;
          float e = __expf(z[j]);
          den[j] += e;
          num[j] = fmaf(ma[jj], e, num[j]);
        }
      }
    }
    // magg -> tanh -> packed f16 pairs (num/den die here, before fc1)
#pragma unroll
    for (int j2 = 0; j2 < 16; ++j2) {
      float ma = num[2 * j2] * __builtin_amdgcn_rcpf(den[2 * j2]);
      float mb = num[2 * j2 + 1] * __builtin_amdgcn_rcpf(den[2 * j2 + 1]);
      xup[32 + j2] = pku(fast_tanh(ma), fast_tanh(mb));
    }
  }

  // ---------------- Phase B: fc1 on cat(x,u) -> h1[64] -----------------------
  {
    float h1[64];
#pragma unroll
    for (int j = 0; j < 64; ++j) h1[j] = b1[j];

    const float4* __restrict__ x4 = reinterpret_cast<const float4*>(x + (size_t)b * S);
    for (int g = 0; g < 8; ++g) {  // dynamic; 8 floats (2 float4) per iter
      float4 va = x4[2 * g], vb = x4[2 * g + 1];
      uint32 p0 = pku(va.x, va.y), p1 = pku(va.z, va.w);
      uint32 p2 = pku(vb.x, vb.y), p3 = pku(vb.z, vb.w);
      const uint32* wb = &wlds[W1P_OFF + (4 * g) * 64];
      dot64(wb, p0, h1);
      dot64(wb + 64, p1, h1);
      dot64(wb + 128, p2, h1);
      dot64(wb + 192, p3, h1);
    }
    const float4* __restrict__ u4 = reinterpret_cast<const float4*>(u + (size_t)b * A);
    for (int g = 0; g < 2; ++g) {  // dynamic; 8 floats per iter
      float4 va = u4[2 * g], vb = u4[2 * g + 1];
      uint32 p0 = pku(va.x, va.y), p1 = pku(va.z, va.w);
      uint32 p2 = pku(vb.x, vb.y), p3 = pku(vb.z, vb.w);
      const uint32* wb = &wlds[W1P_OFF + (32 + 4 * g) * 64];
      dot64(wb, p0, h1);
      dot64(wb + 64, p1, h1);
      dot64(wb + 128, p2, h1);
      dot64(wb + 192, p3, h1);
    }

    // L2 normalize + tanh -> packed pairs
    float s0 = 0.f, s1 = 0.f, s2 = 0.f, s3 = 0.f;
#pragma unroll
    for (int j = 0; j < 64; j += 4) {
      s0 = fmaf(h1[j + 0], h1[j + 0], s0);
      s1 = fmaf(h1[j + 1], h1[j + 1], s1);
      s2 = fmaf(h1[j + 2], h1[j + 2], s2);
      s3 = fmaf(h1[j + 3], h1[j + 3], s3);
    }
    float rn = __builtin_amdgcn_rsqf(fmaxf((s0 + s1) + (s2 + s3), 1e-24f));
#pragma unroll
    for (int j2 = 0; j2 < 32; ++j2)
      xup[j2] = pku(fast_tanh(h1[2 * j2] * rn), fast_tanh(h1[2 * j2 + 1] * rn));
  }

  // ---------------- Phase D: fc2 (2 rows/iter) chained into fc3 --------------
  float o[MSG];
#pragma unroll
  for (int j = 0; j < MSG; ++j) o[j] = b3[j];

  for (int j2 = 0; j2 < 32; ++j2) {  // dynamic; xup indices static
    const uint32* w0 = &wlds[W2P_OFF + (2 * j2) * 48];
    const uint32* w1 = w0 + 48;
    float a0 = b2[2 * j2], a1 = 0.f, a2 = 0.f, a3 = 0.f;
    float c0 = b2[2 * j2 + 1], c1 = 0.f, c2 = 0.f, c3 = 0.f;
#pragma unroll
    for (int k4 = 0; k4 < 12; ++k4) {
      uint4 wa = *reinterpret_cast<const uint4*>(w0 + 4 * k4);
      uint4 wb = *reinterpret_cast<const uint4*>(w1 + 4 * k4);
      a0 = fd(xup[4 * k4 + 0], wa.x, a0);
      a1 = fd(xup[4 * k4 + 1], wa.y, a1);
      a2 = fd(xup[4 * k4 + 2], wa.z, a2);
      a3 = fd(xup[4 * k4 + 3], wa.w, a3);
      c0 = fd(xup[4 * k4 + 0], wb.x, c0);
      c1 = fd(xup[4 * k4 + 1], wb.y, c1);
      c2 = fd(xup[4 * k4 + 2], wb.z, c2);
      c3 = fd(xup[4 * k4 + 3], wb.w, c3);
    }
    uint32 hp = pku(fast_tanh((a0 + a1) + (a2 + a3)),
                    fast_tanh((c0 + c1) + (c2 + c3)));
    const uint32* w3 = &wlds[W3P_OFF + j2 * 32];
#pragma unroll
    for (int q = 0; q < 8; ++q) {
      uint4 wv = *reinterpret_cast<const uint4*>(w3 + 4 * q);
      o[4 * q + 0] = fd(hp, wv.x, o[4 * q + 0]);
      o[4 * q + 1] = fd(hp, wv.y, o[4 * q + 1]);
      o[4 * q + 2] = fd(hp, wv.z, o[4 * q + 2]);
      o[4 * q + 3] = fd(hp, wv.w, o[4 * q + 3]);
    }
  }

  // ---------------- Phase E: final L2 norm + store ---------------------------
  float t0 = 0.f, t1 = 0.f, t2 = 0.f, t3 = 0.f;
#pragma unroll
  for (int j = 0; j < MSG; j += 4) {
    t0 = fmaf(o[j + 0], o[j + 0], t0);
    t1 = fmaf(o[j + 1], o[j + 1], t1);
    t2 = fmaf(o[j + 2], o[j + 2], t2);
    t3 = fmaf(o[j + 3], o[j + 3], t3);
  }
  float rn2 = __builtin_amdgcn_rsqf(fmaxf((t0 + t1) + (t2 + t3), 1e-24f));

  float4* __restrict__ orow = reinterpret_cast<float4*>(out + (size_t)b * MSG);
#pragma unroll
  for (int j4 = 0; j4 < MSG / 4; ++j4) {
    float4 ov;
    ov.x = o[j4 * 4 + 0] * rn2;
    ov.y = o[j4 * 4 + 1] * rn2;
    ov.z = o[j4 * 4 + 2] * rn2;
    ov.w = o[j4 * 4 + 3] * rn2;
    orow[j4] = ov;
  }
}

extern "C" void kernel_launch(void* const* d_in, const int* in_sizes, int n_in,
                              void* d_out, int out_size, void* d_ws, size_t ws_size,
                              hipStream_t stream) {
  const float* x  = (const float*)d_in[0];
  const float* u  = (const float*)d_in[1];
  const float* cs = (const float*)d_in[2];
  const float* m  = (const float*)d_in[3];
  const float* W1 = (const float*)d_in[4];
  const float* b1 = (const float*)d_in[5];
  const float* W2 = (const float*)d_in[6];
  const float* b2 = (const float*)d_in[7];
  const float* W3 = (const float*)d_in[8];
  const float* b3 = (const float*)d_in[9];
  const float* Wa = (const float*)d_in[10];
  const float* ba = (const float*)d_in[11];
  float* out = (float*)d_out;
  uint32* ws = (uint32*)d_ws;

  const int n = in_sizes[0] / S;  // batch rows

  hipLaunchKernelGGL(prep_pack, dim3(12), dim3(256), 0, stream, W1, Wa, W2, W3, ws);

  const int blocks = (n + 255) / 256;
  hipLaunchKernelGGL(critic_fused_kernel, dim3(blocks), dim3(256), 0, stream,
                     x, u, cs, m, b1, b2, b3, ba, ws, out, n);
}

// Round 5
// 271.539 us; speedup vs baseline: 4.1939x; 1.9914x over previous
//
#include <hip/hip_runtime.h>
#include <cstddef>

typedef __fp16 f16x8 __attribute__((ext_vector_type(8)));
typedef float f32x4 __attribute__((ext_vector_type(4)));
typedef unsigned int uint32;
typedef unsigned short ushort;

constexpr int S = 64, MSG = 32, CH = 73;

// frag-linear f16 weight tiles in ws. One tile = 16 cols x 32 k = 64 lanes x 8 f16.
constexpr int FC1_OFF = 0;          // 12 tiles (t0..2 x f0..3)  K=96 (80 real + bias@80)
constexpr int ATT_OFF = 12 * 512;   // 6 tiles  (t0..2 x f0..1)  K=96 (73 real + bias@73)
constexpr int FC2_OFF = 18 * 512;   // 12 tiles (t0..2 x f0..3)  K=96 exact (bias separate)
constexpr int FC3_OFF = 30 * 512;   // 4 tiles  (t0..1 x f0..1)  K=64 exact (bias separate)
constexpr int WS_ELEMS = 34 * 512;  // 17408 ushort = 34816 B

__global__ void prep_pack(const float* __restrict__ W1, const float* __restrict__ b1,
                          const float* __restrict__ Wa, const float* __restrict__ ba,
                          const float* __restrict__ W2, const float* __restrict__ W3,
                          ushort* __restrict__ wsf) {
  int idx = blockIdx.x * 256 + threadIdx.x;
  if (idx >= WS_ELEMS) return;
  int tile = idx >> 9;
  int lane = (idx >> 3) & 63;
  int e = idx & 7;
  int jloc = lane & 15;
  int kloc = ((lane >> 4) << 3) + e;  // B-frag: lane holds B[k][col=lane&15], k=(lane>>4)*8+e
  float v = 0.f;
  if (tile < 12) {                       // W1 [64][80]
    int t = tile >> 2, f = tile & 3;
    int j = f * 16 + jloc, k = t * 32 + kloc;
    v = (k < 80) ? W1[j * 80 + k] : (k == 80 ? b1[j] : 0.f);
  } else if (tile < 18) {                // Wa [32][73]
    int q = tile - 12, t = q >> 1, f = q & 1;
    int j = f * 16 + jloc, k = t * 32 + kloc;
    v = (k < 73) ? Wa[j * 73 + k] : (k == 73 ? ba[j] : 0.f);
  } else if (tile < 30) {                // W2 [64][96]
    int q = tile - 18, t = q >> 2, f = q & 3;
    int j = f * 16 + jloc, k = t * 32 + kloc;
    v = W2[j * 96 + k];
  } else {                               // W3 [32][64]
    int q = tile - 30, t = q >> 1, f = q & 1;
    int j = f * 16 + jloc, k = t * 32 + kloc;
    v = W3[j * 64 + k];
  }
  union { __fp16 h; ushort s; } cv;
  cv.h = (__fp16)v;
  wsf[idx] = cv.s;
}

__device__ __forceinline__ f32x4 mf(f16x8 a, f16x8 b, f32x4 c) {
  return __builtin_amdgcn_mfma_f32_16x16x32_f16(a, b, c, 0, 0, 0);
}
__device__ __forceinline__ uint32 pku(float a, float b) {
  auto r = __builtin_amdgcn_cvt_pkrtz(a, b);
  union { decltype(r) f; uint32 u; } v; v.f = r; return v.u;
}
__device__ __forceinline__ f16x8 packA(const float* f) {
  union { uint32 u[4]; f16x8 h; } r;
  r.u[0] = pku(f[0], f[1]); r.u[1] = pku(f[2], f[3]);
  r.u[2] = pku(f[4], f[5]); r.u[3] = pku(f[6], f[7]);
  return r.h;
}
__device__ __forceinline__ float fast_tanh(float v) {
  v = fminf(15.f, fmaxf(-15.f, v));
  float t = __expf(2.f * v);
  return (t - 1.f) * __builtin_amdgcn_rcpf(t + 1.f);
}

__launch_bounds__(256)
__global__ void critic_mfma_kernel(
    const float* __restrict__ x, const float* __restrict__ u,
    const float* __restrict__ cs, const float* __restrict__ m,
    const float* __restrict__ b2, const float* __restrict__ b3,
    const ushort* __restrict__ wsf, float* __restrict__ out, int n) {
  __shared__ __attribute__((aligned(16))) __fp16 hbuf[4][16 * 96];   // fc2 input tiles
  __shared__ __attribute__((aligned(16))) __fp16 h2buf[4][16 * 64];  // fc3 input tiles

  const int wave = threadIdx.x >> 6;
  const int lane = threadIdx.x & 63;
  const int lm = lane & 15;
  const int lq = lane >> 4;
  const int r0 = (blockIdx.x * 4 + wave) * 16;  // this wave's 16 rows
  if (r0 >= n) return;

  __fp16* __restrict__ ht = &hbuf[wave][0];    // [16][96]
  __fp16* __restrict__ h2t = &h2buf[wave][0];  // [16][64]

  auto ldB = [&](int off_tile) -> f16x8 {
    return *reinterpret_cast<const f16x8*>(wsf + off_tile + lane * 8);
  };

  // ============ Attention: rows are (b,c); 4 subtiles of 4 b's ============
  f16x8 wa[6];
#pragma unroll
  for (int i = 0; i < 6; ++i) wa[i] = ldB(ATT_OFF + i * 512);

#pragma unroll
  for (int g = 0; g < 4; ++g) {
    // A row index (l&15) -> (b, c)
    const int bb = r0 + 4 * g + (lm >> 2);
    const int cc = lm & 3;
    const float* __restrict__ csrow = cs + ((size_t)bb * 4 + cc) * CH;
    f32x4 zac[2] = {{0.f, 0.f, 0.f, 0.f}, {0.f, 0.f, 0.f, 0.f}};
#pragma unroll
    for (int t = 0; t < 3; ++t) {
      float f[8];
      const int kbase = t * 32 + lq * 8;
#pragma unroll
      for (int e = 0; e < 8; ++e) {
        int k = kbase + e;
        f[e] = (t < 2) ? csrow[k]
                       : ((k < 73) ? csrow[k] : (k == 73 ? 1.f : 0.f));
      }
      f16x8 af = packA(f);
      zac[0] = mf(af, wa[t * 2 + 0], zac[0]);
      zac[1] = mf(af, wa[t * 2 + 1], zac[1]);
    }
    // D rows: row=4*lq'... here row=(4*(lane>>4)+reg) -> b = r0+4g+lq, c = reg
    const int bo = r0 + 4 * g + lq;
    const float* __restrict__ mrow = m + (size_t)bo * 128;
#pragma unroll
    for (int f = 0; f < 2; ++f) {
      const int j = lm + 16 * f;
      float e0 = __expf(zac[f][0]);
      float e1 = __expf(zac[f][1]);
      float e2 = __expf(zac[f][2]);
      float e3 = __expf(zac[f][3]);
      float den = (e0 + e1) + (e2 + e3);
      float num = fmaf(mrow[0 * 32 + j], e0,
                  fmaf(mrow[1 * 32 + j], e1,
                  fmaf(mrow[2 * 32 + j], e2, mrow[3 * 32 + j] * e3)));
      float mg = num * __builtin_amdgcn_rcpf(den);
      ht[(4 * g + lq) * 96 + 64 + j] = (__fp16)fast_tanh(mg);
    }
  }

  // ============ fc1: cat(x,u,1) [16x96] @ W1T ============
  f32x4 hac[4] = {{0.f,0.f,0.f,0.f},{0.f,0.f,0.f,0.f},{0.f,0.f,0.f,0.f},{0.f,0.f,0.f,0.f}};
  {
    const float* __restrict__ xrow = x + (size_t)(r0 + lm) * S;
    const float* __restrict__ urow = u + (size_t)(r0 + lm) * 16;
#pragma unroll
    for (int t = 0; t < 2; ++t) {
      const float4* p = reinterpret_cast<const float4*>(xrow + t * 32 + lq * 8);
      float4 va = p[0], vb = p[1];
      float f[8] = {va.x, va.y, va.z, va.w, vb.x, vb.y, vb.z, vb.w};
      f16x8 af = packA(f);
#pragma unroll
      for (int fi = 0; fi < 4; ++fi)
        hac[fi] = mf(af, ldB(FC1_OFF + (t * 4 + fi) * 512), hac[fi]);
    }
    {  // t = 2: k = 64..95 -> u part + bias-one
      float f[8];
      const int kbase = 64 + lq * 8;
#pragma unroll
      for (int e = 0; e < 8; ++e) {
        int k = kbase + e;
        f[e] = (k < 80) ? urow[k - 64] : (k == 80 ? 1.f : 0.f);
      }
      f16x8 af = packA(f);
#pragma unroll
      for (int fi = 0; fi < 4; ++fi)
        hac[fi] = mf(af, ldB(FC1_OFF + (2 * 4 + fi) * 512), hac[fi]);
    }
  }
  // L2 normalize rows of h1, tanh, stash to ht cols 0..63
  {
    float rn[4];
#pragma unroll
    for (int reg = 0; reg < 4; ++reg) {
      float s = hac[0][reg] * hac[0][reg];
      s = fmaf(hac[1][reg], hac[1][reg], s);
      s = fmaf(hac[2][reg], hac[2][reg], s);
      s = fmaf(hac[3][reg], hac[3][reg], s);
      s += __shfl_xor(s, 1);
      s += __shfl_xor(s, 2);
      s += __shfl_xor(s, 4);
      s += __shfl_xor(s, 8);
      rn[reg] = __builtin_amdgcn_rcpf(fmaxf(sqrtf(s), 1e-12f));
    }
#pragma unroll
    for (int fi = 0; fi < 4; ++fi)
#pragma unroll
      for (int reg = 0; reg < 4; ++reg)
        ht[(4 * lq + reg) * 96 + lm + 16 * fi] =
            (__fp16)fast_tanh(hac[fi][reg] * rn[reg]);
  }

  // ============ fc2: [16x96] @ W2T + b2, tanh ============
  {
    f32x4 ac2[4] = {{0.f,0.f,0.f,0.f},{0.f,0.f,0.f,0.f},{0.f,0.f,0.f,0.f},{0.f,0.f,0.f,0.f}};
    f16x8 a2[3];
#pragma unroll
    for (int t = 0; t < 3; ++t)
      a2[t] = *reinterpret_cast<const f16x8*>(ht + lm * 96 + t * 32 + lq * 8);
#pragma unroll
    for (int t = 0; t < 3; ++t)
#pragma unroll
      for (int fi = 0; fi < 4; ++fi)
        ac2[fi] = mf(a2[t], ldB(FC2_OFF + (t * 4 + fi) * 512), ac2[fi]);
#pragma unroll
    for (int fi = 0; fi < 4; ++fi) {
      float bv = b2[lm + 16 * fi];
#pragma unroll
      for (int reg = 0; reg < 4; ++reg)
        h2t[(4 * lq + reg) * 64 + lm + 16 * fi] =
            (__fp16)fast_tanh(ac2[fi][reg] + bv);
    }
  }

  // ============ fc3: [16x64] @ W3T + b3, L2 norm, store ============
  {
    f32x4 o[2] = {{0.f,0.f,0.f,0.f},{0.f,0.f,0.f,0.f}};
    f16x8 a3[2];
#pragma unroll
    for (int t = 0; t < 2; ++t)
      a3[t] = *reinterpret_cast<const f16x8*>(h2t + lm * 64 + t * 32 + lq * 8);
#pragma unroll
    for (int t = 0; t < 2; ++t)
#pragma unroll
      for (int fi = 0; fi < 2; ++fi)
        o[fi] = mf(a3[t], ldB(FC3_OFF + (t * 2 + fi) * 512), o[fi]);
#pragma unroll
    for (int fi = 0; fi < 2; ++fi) {
      float bv = b3[lm + 16 * fi];
#pragma unroll
      for (int reg = 0; reg < 4; ++reg) o[fi][reg] += bv;
    }
    float rn2[4];
#pragma unroll
    for (int reg = 0; reg < 4; ++reg) {
      float s = fmaf(o[0][reg], o[0][reg], o[1][reg] * o[1][reg]);
      s += __shfl_xor(s, 1);
      s += __shfl_xor(s, 2);
      s += __shfl_xor(s, 4);
      s += __shfl_xor(s, 8);
      rn2[reg] = __builtin_amdgcn_rcpf(fmaxf(sqrtf(s), 1e-12f));
    }
#pragma unroll
    for (int fi = 0; fi < 2; ++fi)
#pragma unroll
      for (int reg = 0; reg < 4; ++reg)
        out[(size_t)(r0 + 4 * lq + reg) * MSG + lm + 16 * fi] =
            o[fi][reg] * rn2[reg];
  }
}

extern "C" void kernel_launch(void* const* d_in, const int* in_sizes, int n_in,
                              void* d_out, int out_size, void* d_ws, size_t ws_size,
                              hipStream_t stream) {
  const float* x  = (const float*)d_in[0];
  const float* u  = (const float*)d_in[1];
  const float* cs = (const float*)d_in[2];
  const float* m  = (const float*)d_in[3];
  const float* W1 = (const float*)d_in[4];
  const float* b1 = (const float*)d_in[5];
  const float* W2 = (const float*)d_in[6];
  const float* b2 = (const float*)d_in[7];
  const float* W3 = (const float*)d_in[8];
  const float* b3 = (const float*)d_in[9];
  const float* Wa = (const float*)d_in[10];
  const float* ba = (const float*)d_in[11];
  float* out = (float*)d_out;
  ushort* wsf = (ushort*)d_ws;

  const int n = in_sizes[0] / S;  // batch rows

  hipLaunchKernelGGL(prep_pack, dim3((WS_ELEMS + 255) / 256), dim3(256), 0, stream,
                     W1, b1, Wa, ba, W2, W3, wsf);

  const int blocks = (n + 63) / 64;  // 64 rows per block (4 waves x 16)
  hipLaunchKernelGGL(critic_mfma_kernel, dim3(blocks), dim3(256), 0, stream,
                     x, u, cs, m, b2, b3, wsf, out, n);
}

// Round 6
// 231.671 us; speedup vs baseline: 4.9156x; 1.1721x over previous
//
#include <hip/hip_runtime.h>
#include <cstddef>

typedef __fp16 f16x8 __attribute__((ext_vector_type(8)));
typedef float f32x4 __attribute__((ext_vector_type(4)));
typedef unsigned int uint32;
typedef unsigned short ushort;

constexpr int S = 64, MSG = 32, CH = 73;

// frag-linear f16 weight tiles in ws. One tile = 16 cols x 32 k = 64 lanes x 8 f16.
constexpr int FC1_OFF = 0;          // 12 tiles (t0..2 x f0..3)  K=96 (80 real + bias@80)
constexpr int ATT_OFF = 12 * 512;   // 6 tiles  (t0..2 x f0..1)  K=96 (73 real + bias@73)
constexpr int FC2_OFF = 18 * 512;   // 12 tiles (t0..2 x f0..3)  K=96 exact (bias separate)
constexpr int FC3_OFF = 30 * 512;   // 4 tiles  (t0..1 x f0..1)  K=64 exact (bias separate)
constexpr int WS_ELEMS = 34 * 512;  // 17408 ushort = 34816 B

__global__ void prep_pack(const float* __restrict__ W1, const float* __restrict__ b1,
                          const float* __restrict__ Wa, const float* __restrict__ ba,
                          const float* __restrict__ W2, const float* __restrict__ W3,
                          ushort* __restrict__ wsf) {
  int idx = blockIdx.x * 256 + threadIdx.x;
  if (idx >= WS_ELEMS) return;
  int tile = idx >> 9;
  int lane = (idx >> 3) & 63;
  int e = idx & 7;
  int jloc = lane & 15;
  int kloc = ((lane >> 4) << 3) + e;  // B-frag: lane holds B[k][col=lane&15], k=(lane>>4)*8+e
  float v = 0.f;
  if (tile < 12) {                       // W1 [64][80]
    int t = tile >> 2, f = tile & 3;
    int j = f * 16 + jloc, k = t * 32 + kloc;
    v = (k < 80) ? W1[j * 80 + k] : (k == 80 ? b1[j] : 0.f);
  } else if (tile < 18) {                // Wa [32][73]
    int q = tile - 12, t = q >> 1, f = q & 1;
    int j = f * 16 + jloc, k = t * 32 + kloc;
    v = (k < 73) ? Wa[j * 73 + k] : (k == 73 ? ba[j] : 0.f);
  } else if (tile < 30) {                // W2 [64][96]
    int q = tile - 18, t = q >> 2, f = q & 3;
    int j = f * 16 + jloc, k = t * 32 + kloc;
    v = W2[j * 96 + k];
  } else {                               // W3 [32][64]
    int q = tile - 30, t = q >> 1, f = q & 1;
    int j = f * 16 + jloc, k = t * 32 + kloc;
    v = W3[j * 64 + k];
  }
  union { __fp16 h; ushort s; } cv;
  cv.h = (__fp16)v;
  wsf[idx] = cv.s;
}

__device__ __forceinline__ f32x4 mf(f16x8 a, f16x8 b, f32x4 c) {
  return __builtin_amdgcn_mfma_f32_16x16x32_f16(a, b, c, 0, 0, 0);
}
__device__ __forceinline__ uint32 pku(float a, float b) {
  auto r = __builtin_amdgcn_cvt_pkrtz(a, b);
  union { decltype(r) f; uint32 u; } v; v.f = r; return v.u;
}
__device__ __forceinline__ f16x8 packA(const float* f) {
  union { uint32 u[4]; f16x8 h; } r;
  r.u[0] = pku(f[0], f[1]); r.u[1] = pku(f[2], f[3]);
  r.u[2] = pku(f[4], f[5]); r.u[3] = pku(f[6], f[7]);
  return r.h;
}
__device__ __forceinline__ f16x8 packA2(float4 a, float4 b) {
  union { uint32 u[4]; f16x8 h; } r;
  r.u[0] = pku(a.x, a.y); r.u[1] = pku(a.z, a.w);
  r.u[2] = pku(b.x, b.y); r.u[3] = pku(b.z, b.w);
  return r.h;
}
__device__ __forceinline__ float fast_tanh(float v) {
  v = fminf(15.f, fmaxf(-15.f, v));
  float t = __expf(2.f * v);
  return (t - 1.f) * __builtin_amdgcn_rcpf(t + 1.f);
}

constexpr int HT_LD = 104;  // padded f16 stride (2-way banks only)
constexpr int H2_LD = 72;

__launch_bounds__(256)
__global__ void critic_mfma_kernel(
    const float* __restrict__ x, const float* __restrict__ u,
    const float* __restrict__ cs, const float* __restrict__ m,
    const float* __restrict__ b2, const float* __restrict__ b3,
    const ushort* __restrict__ wsf, float* __restrict__ out, int n) {
  __shared__ __attribute__((aligned(16))) float csb[4][1168];      // per-wave cs chunk
  __shared__ __attribute__((aligned(16))) __fp16 hbuf[4][16 * HT_LD];
  __shared__ __attribute__((aligned(16))) __fp16 h2buf[4][16 * H2_LD];

  const int wave = threadIdx.x >> 6;
  const int lane = threadIdx.x & 63;
  const int lm = lane & 15;
  const int lq = lane >> 4;
  const int r0 = (blockIdx.x * 4 + wave) * 16;  // this wave's 16 rows
  if (r0 >= n) return;

  float* __restrict__ csw = &csb[wave][0];
  __fp16* __restrict__ ht = &hbuf[wave][0];    // [16][HT_LD]
  __fp16* __restrict__ h2t = &h2buf[wave][0];  // [16][H2_LD]

  // -------- prefetch x,u rows into registers (consumed in fc1, hidden under attn)
  const float4* __restrict__ xrow4 =
      reinterpret_cast<const float4*>(x + (size_t)(r0 + lm) * S);
  float4 xva = xrow4[2 * lq], xvb = xrow4[2 * lq + 1];
  float4 xvc = xrow4[8 + 2 * lq], xvd = xrow4[9 + 2 * lq];
  const int uq = (lq < 2) ? lq : 0;  // clamp: lanes lq>=2 don't use u (avoids OOB)
  const float4* __restrict__ urow4 =
      reinterpret_cast<const float4*>(u + (size_t)(r0 + lm) * 16);
  float4 uva = urow4[2 * uq], uvb = urow4[2 * uq + 1];

  auto ldB = [&](int off_tile) -> f16x8 {
    return *reinterpret_cast<const f16x8*>(wsf + off_tile + lane * 8);
  };

  // ============ Attention: rows are (b,c); 4 subtiles of 16 att-rows ============
  f16x8 wa[6];
#pragma unroll
  for (int i = 0; i < 6; ++i) wa[i] = ldB(ATT_OFF + i * 512);

#pragma unroll
  for (int g = 0; g < 4; ++g) {
    // stage 16 contiguous (b,c) rows = 4672 B, fully coalesced (292 float4)
    {
      const float4* __restrict__ src =
          reinterpret_cast<const float4*>(cs + (size_t)(r0 * 4 + 16 * g) * CH);
      float4* __restrict__ dst = reinterpret_cast<float4*>(csw);
#pragma unroll
      for (int i = 0; i < 4; ++i) dst[i * 64 + lane] = src[i * 64 + lane];
      if (lane < 36) dst[256 + lane] = src[256 + lane];
    }
    // A-fragments from LDS (wave-private; lgkmcnt orders write->read)
    const float* __restrict__ crow = csw + lm * CH;
    f32x4 zac[2] = {{0.f, 0.f, 0.f, 0.f}, {0.f, 0.f, 0.f, 0.f}};
#pragma unroll
    for (int t = 0; t < 3; ++t) {
      float f[8];
      const int kbase = t * 32 + lq * 8;
#pragma unroll
      for (int e = 0; e < 8; ++e) {
        int k = kbase + e;
        f[e] = (k < 73) ? crow[k] : (k == 73 ? 1.f : 0.f);
      }
      f16x8 af = packA(f);
      zac[0] = mf(af, wa[t * 2 + 0], zac[0]);
      zac[1] = mf(af, wa[t * 2 + 1], zac[1]);
    }
    // D rows: row=4*lq+reg -> b = r0+4g+lq, c = reg
    const int bo = r0 + 4 * g + lq;
    const float* __restrict__ mrow = m + (size_t)bo * 128;
#pragma unroll
    for (int f = 0; f < 2; ++f) {
      const int j = lm + 16 * f;
      float e0 = __expf(zac[f][0]);
      float e1 = __expf(zac[f][1]);
      float e2 = __expf(zac[f][2]);
      float e3 = __expf(zac[f][3]);
      float den = (e0 + e1) + (e2 + e3);
      float num = fmaf(mrow[0 * 32 + j], e0,
                  fmaf(mrow[1 * 32 + j], e1,
                  fmaf(mrow[2 * 32 + j], e2, mrow[3 * 32 + j] * e3)));
      float mg = num * __builtin_amdgcn_rcpf(den);
      ht[(4 * g + lq) * HT_LD + 64 + j] = (__fp16)fast_tanh(mg);
    }
  }

  // ============ fc1: cat(x,u,1) [16x96] @ W1T ============
  f32x4 hac[4] = {{0.f,0.f,0.f,0.f},{0.f,0.f,0.f,0.f},{0.f,0.f,0.f,0.f},{0.f,0.f,0.f,0.f}};
  {
    f16x8 a0 = packA2(xva, xvb);
    f16x8 a1 = packA2(xvc, xvd);
#pragma unroll
    for (int fi = 0; fi < 4; ++fi) hac[fi] = mf(a0, ldB(FC1_OFF + fi * 512), hac[fi]);
#pragma unroll
    for (int fi = 0; fi < 4; ++fi) hac[fi] = mf(a1, ldB(FC1_OFF + (4 + fi) * 512), hac[fi]);
    // t = 2: k = 64..95 -> u part (lq 0,1) + bias-one (k==80) + zeros
    float f[8];
    float uf[8] = {uva.x, uva.y, uva.z, uva.w, uvb.x, uvb.y, uvb.z, uvb.w};
#pragma unroll
    for (int e = 0; e < 8; ++e) {
      int k = 64 + lq * 8 + e;
      f[e] = (k < 80) ? ((lq < 2) ? uf[e] : 0.f) : (k == 80 ? 1.f : 0.f);
    }
    f16x8 a2f = packA(f);
#pragma unroll
    for (int fi = 0; fi < 4; ++fi) hac[fi] = mf(a2f, ldB(FC1_OFF + (8 + fi) * 512), hac[fi]);
  }
  // L2 normalize rows of h1, tanh, stash to ht cols 0..63
  {
    float rn[4];
#pragma unroll
    for (int reg = 0; reg < 4; ++reg) {
      float s = hac[0][reg] * hac[0][reg];
      s = fmaf(hac[1][reg], hac[1][reg], s);
      s = fmaf(hac[2][reg], hac[2][reg], s);
      s = fmaf(hac[3][reg], hac[3][reg], s);
      s += __shfl_xor(s, 1);
      s += __shfl_xor(s, 2);
      s += __shfl_xor(s, 4);
      s += __shfl_xor(s, 8);
      rn[reg] = __builtin_amdgcn_rcpf(fmaxf(sqrtf(s), 1e-12f));
    }
#pragma unroll
    for (int fi = 0; fi < 4; ++fi)
#pragma unroll
      for (int reg = 0; reg < 4; ++reg)
        ht[(4 * lq + reg) * HT_LD + lm + 16 * fi] =
            (__fp16)fast_tanh(hac[fi][reg] * rn[reg]);
  }

  // ============ fc2: [16x96] @ W2T + b2, tanh ============
  {
    f32x4 ac2[4] = {{0.f,0.f,0.f,0.f},{0.f,0.f,0.f,0.f},{0.f,0.f,0.f,0.f},{0.f,0.f,0.f,0.f}};
    f16x8 a2[3];
#pragma unroll
    for (int t = 0; t < 3; ++t)
      a2[t] = *reinterpret_cast<const f16x8*>(ht + lm * HT_LD + t * 32 + lq * 8);
#pragma unroll
    for (int t = 0; t < 3; ++t)
#pragma unroll
      for (int fi = 0; fi < 4; ++fi)
        ac2[fi] = mf(a2[t], ldB(FC2_OFF + (t * 4 + fi) * 512), ac2[fi]);
#pragma unroll
    for (int fi = 0; fi < 4; ++fi) {
      float bv = b2[lm + 16 * fi];
#pragma unroll
      for (int reg = 0; reg < 4; ++reg)
        h2t[(4 * lq + reg) * H2_LD + lm + 16 * fi] =
            (__fp16)fast_tanh(ac2[fi][reg] + bv);
    }
  }

  // ============ fc3: [16x64] @ W3T + b3, L2 norm, store ============
  {
    f32x4 o[2] = {{0.f,0.f,0.f,0.f},{0.f,0.f,0.f,0.f}};
    f16x8 a3[2];
#pragma unroll
    for (int t = 0; t < 2; ++t)
      a3[t] = *reinterpret_cast<const f16x8*>(h2t + lm * H2_LD + t * 32 + lq * 8);
#pragma unroll
    for (int t = 0; t < 2; ++t)
#pragma unroll
      for (int fi = 0; fi < 2; ++fi)
        o[fi] = mf(a3[t], ldB(FC3_OFF + (t * 2 + fi) * 512), o[fi]);
#pragma unroll
    for (int fi = 0; fi < 2; ++fi) {
      float bv = b3[lm + 16 * fi];
#pragma unroll
      for (int reg = 0; reg < 4; ++reg) o[fi][reg] += bv;
    }
    float rn2[4];
#pragma unroll
    for (int reg = 0; reg < 4; ++reg) {
      float s = fmaf(o[0][reg], o[0][reg], o[1][reg] * o[1][reg]);
      s += __shfl_xor(s, 1);
      s += __shfl_xor(s, 2);
      s += __shfl_xor(s, 4);
      s += __shfl_xor(s, 8);
      rn2[reg] = __builtin_amdgcn_rcpf(fmaxf(sqrtf(s), 1e-12f));
    }
#pragma unroll
    for (int fi = 0; fi < 2; ++fi)
#pragma unroll
      for (int reg = 0; reg < 4; ++reg)
        out[(size_t)(r0 + 4 * lq + reg) * MSG + lm + 16 * fi] =
            o[fi][reg] * rn2[reg];
  }
}

extern "C" void kernel_launch(void* const* d_in, const int* in_sizes, int n_in,
                              void* d_out, int out_size, void* d_ws, size_t ws_size,
                              hipStream_t stream) {
  const float* x  = (const float*)d_in[0];
  const float* u  = (const float*)d_in[1];
  const float* cs = (const float*)d_in[2];
  const float* m  = (const float*)d_in[3];
  const float* W1 = (const float*)d_in[4];
  const float* b1 = (const float*)d_in[5];
  const float* W2 = (const float*)d_in[6];
  const float* b2 = (const float*)d_in[7];
  const float* W3 = (const float*)d_in[8];
  const float* b3 = (const float*)d_in[9];
  const float* Wa = (const float*)d_in[10];
  const float* ba = (const float*)d_in[11];
  float* out = (float*)d_out;
  ushort* wsf = (ushort*)d_ws;

  const int n = in_sizes[0] / S;  // batch rows

  hipLaunchKernelGGL(prep_pack, dim3((WS_ELEMS + 255) / 256), dim3(256), 0, stream,
                     W1, b1, Wa, ba, W2, W3, wsf);

  const int blocks = (n + 63) / 64;  // 64 rows per block (4 waves x 16)
  hipLaunchKernelGGL(critic_mfma_kernel, dim3(blocks), dim3(256), 0, stream,
                     x, u, cs, m, b2, b3, wsf, out, n);
}

// Round 7
// 223.783 us; speedup vs baseline: 5.0888x; 1.0352x over previous
//
#include <hip/hip_runtime.h>
#include <cstddef>

typedef __fp16 f16x8 __attribute__((ext_vector_type(8)));
typedef float f32x4 __attribute__((ext_vector_type(4)));
typedef unsigned int uint32;
typedef unsigned short ushort;

constexpr int S = 64, MSG = 32, CH = 73;

// frag-linear f16 weight tiles in ws. One tile = 16 cols x 32 k = 64 lanes x 8 f16.
constexpr int FC1_OFF = 0;          // 12 tiles (t0..2 x f0..3)  K=96 (80 real + bias@80)
constexpr int ATT_OFF = 12 * 512;   // 6 tiles  (t0..2 x f0..1)  K=96 (73 real + bias@73)
constexpr int FC2_OFF = 18 * 512;   // 12 tiles (t0..2 x f0..3)  K=96 exact (bias separate)
constexpr int FC3_OFF = 30 * 512;   // 4 tiles  (t0..1 x f0..1)  K=64 exact (bias separate)
constexpr int WS_ELEMS = 34 * 512;  // 17408 ushort = 34816 B

__global__ void prep_pack(const float* __restrict__ W1, const float* __restrict__ b1,
                          const float* __restrict__ Wa, const float* __restrict__ ba,
                          const float* __restrict__ W2, const float* __restrict__ W3,
                          ushort* __restrict__ wsf) {
  int idx = blockIdx.x * 256 + threadIdx.x;
  if (idx >= WS_ELEMS) return;
  int tile = idx >> 9;
  int lane = (idx >> 3) & 63;
  int e = idx & 7;
  int jloc = lane & 15;
  int kloc = ((lane >> 4) << 3) + e;  // B-frag: lane holds B[k][col=lane&15], k=(lane>>4)*8+e
  float v = 0.f;
  if (tile < 12) {                       // W1 [64][80]
    int t = tile >> 2, f = tile & 3;
    int j = f * 16 + jloc, k = t * 32 + kloc;
    v = (k < 80) ? W1[j * 80 + k] : (k == 80 ? b1[j] : 0.f);
  } else if (tile < 18) {                // Wa [32][73]
    int q = tile - 12, t = q >> 1, f = q & 1;
    int j = f * 16 + jloc, k = t * 32 + kloc;
    v = (k < 73) ? Wa[j * 73 + k] : (k == 73 ? ba[j] : 0.f);
  } else if (tile < 30) {                // W2 [64][96]
    int q = tile - 18, t = q >> 2, f = q & 3;
    int j = f * 16 + jloc, k = t * 32 + kloc;
    v = W2[j * 96 + k];
  } else {                               // W3 [32][64]
    int q = tile - 30, t = q >> 1, f = q & 1;
    int j = f * 16 + jloc, k = t * 32 + kloc;
    v = W3[j * 64 + k];
  }
  union { __fp16 h; ushort s; } cv;
  cv.h = (__fp16)v;
  wsf[idx] = cv.s;
}

__device__ __forceinline__ f32x4 mf(f16x8 a, f16x8 b, f32x4 c) {
  return __builtin_amdgcn_mfma_f32_16x16x32_f16(a, b, c, 0, 0, 0);
}
__device__ __forceinline__ uint32 pku(float a, float b) {
  auto r = __builtin_amdgcn_cvt_pkrtz(a, b);
  union { decltype(r) f; uint32 u; } v; v.f = r; return v.u;
}
__device__ __forceinline__ f16x8 packA(const float* f) {
  union { uint32 u[4]; f16x8 h; } r;
  r.u[0] = pku(f[0], f[1]); r.u[1] = pku(f[2], f[3]);
  r.u[2] = pku(f[4], f[5]); r.u[3] = pku(f[6], f[7]);
  return r.h;
}
__device__ __forceinline__ f16x8 packA2(float4 a, float4 b) {
  union { uint32 u[4]; f16x8 h; } r;
  r.u[0] = pku(a.x, a.y); r.u[1] = pku(a.z, a.w);
  r.u[2] = pku(b.x, b.y); r.u[3] = pku(b.z, b.w);
  return r.h;
}
__device__ __forceinline__ float fast_tanh(float v) {
  v = fminf(15.f, fmaxf(-15.f, v));
  float t = __expf(2.f * v);
  return (t - 1.f) * __builtin_amdgcn_rcpf(t + 1.f);
}

constexpr int HT_LD = 104;  // f16 stride; 208 B (16B-aligned rows)
constexpr int H2_LD = 72;   // f16 stride; 144 B
// per-block smem: hbuf 4w x 3328 B = 13312; then per-wave union region 4672 B
// (csb during attention | h2buf after fc2) x 4w = 18688. total 32000 B.
constexpr int HBUF_B = 3328;
constexpr int UNION_OFF = 13312;
constexpr int UNION_B = 4672;
constexpr int SMEM_B = 32000;

__launch_bounds__(256)
__global__ void critic_mfma_kernel(
    const float* __restrict__ x, const float* __restrict__ u,
    const float* __restrict__ cs, const float* __restrict__ m,
    const float* __restrict__ b2, const float* __restrict__ b3,
    const ushort* __restrict__ wsf, float* __restrict__ out, int n) {
  __shared__ __attribute__((aligned(16))) unsigned char smem[SMEM_B];

  const int wave = threadIdx.x >> 6;
  const int lane = threadIdx.x & 63;
  const int lm = lane & 15;
  const int lq = lane >> 4;
  const int r0 = (blockIdx.x * 4 + wave) * 16;  // this wave's 16 rows
  if (r0 >= n) return;

  __fp16* __restrict__ ht = reinterpret_cast<__fp16*>(smem + wave * HBUF_B);
  float* __restrict__ csw = reinterpret_cast<float*>(smem + UNION_OFF + wave * UNION_B);
  __fp16* __restrict__ h2t = reinterpret_cast<__fp16*>(smem + UNION_OFF + wave * UNION_B);

  // -------- prefetch x,u rows into registers (consumed in fc1, hidden under attn)
  const float4* __restrict__ xrow4 =
      reinterpret_cast<const float4*>(x + (size_t)(r0 + lm) * S);
  float4 xva = xrow4[2 * lq], xvb = xrow4[2 * lq + 1];
  float4 xvc = xrow4[8 + 2 * lq], xvd = xrow4[9 + 2 * lq];
  const int uq = (lq < 2) ? lq : 0;  // clamp: lanes lq>=2 don't use u (avoids OOB)
  const float4* __restrict__ urow4 =
      reinterpret_cast<const float4*>(u + (size_t)(r0 + lm) * 16);
  float4 uva = urow4[2 * uq], uvb = urow4[2 * uq + 1];

  auto ldB = [&](int off_tile) -> f16x8 {
    return *reinterpret_cast<const f16x8*>(wsf + off_tile + lane * 8);
  };

  // ============ Attention: rows are (b,c); 4 subtiles, reg-staged pipeline ====
  f16x8 wa[6];
#pragma unroll
  for (int i = 0; i < 6; ++i) wa[i] = ldB(ATT_OFF + i * 512);

  // prologue: fetch g=0 chunk (16 contiguous att-rows = 4672 B, coalesced)
  float4 csr0, csr1, csr2, csr3, csr4;
  {
    const float4* __restrict__ src =
        reinterpret_cast<const float4*>(cs + (size_t)(r0 * 4) * CH);
    csr0 = src[lane];       csr1 = src[64 + lane];
    csr2 = src[128 + lane]; csr3 = src[192 + lane];
    if (lane < 36) csr4 = src[256 + lane];
  }

#pragma unroll
  for (int g = 0; g < 4; ++g) {
    // commit staged regs to LDS (DS ops in-order per wave: prior reads done)
    {
      float4* __restrict__ dst = reinterpret_cast<float4*>(csw);
      dst[lane] = csr0;       dst[64 + lane] = csr1;
      dst[128 + lane] = csr2; dst[192 + lane] = csr3;
      if (lane < 36) dst[256 + lane] = csr4;
    }
    // prefetch this g's m scalars FIRST (waited on by softmax via counted vmcnt)
    float mr[8];
    {
      const float* __restrict__ mrow = m + (size_t)(r0 + 4 * g + lq) * 128;
#pragma unroll
      for (int c = 0; c < 4; ++c) {
        mr[c * 2 + 0] = mrow[c * 32 + lm];
        mr[c * 2 + 1] = mrow[c * 32 + lm + 16];
      }
    }
    // then issue next chunk's global loads (stay in flight through this g)
    if (g < 3) {
      const float4* __restrict__ src =
          reinterpret_cast<const float4*>(cs + (size_t)(r0 * 4 + 16 * (g + 1)) * CH);
      csr0 = src[lane];       csr1 = src[64 + lane];
      csr2 = src[128 + lane]; csr3 = src[192 + lane];
      if (lane < 36) csr4 = src[256 + lane];
    }
    // A-fragments from LDS (wave-private; lgkmcnt orders write->read)
    const float* __restrict__ crow = csw + lm * CH;
    f32x4 zac[2] = {{0.f, 0.f, 0.f, 0.f}, {0.f, 0.f, 0.f, 0.f}};
#pragma unroll
    for (int t = 0; t < 3; ++t) {
      float f[8];
      const int kbase = t * 32 + lq * 8;
#pragma unroll
      for (int e = 0; e < 8; ++e) {
        int k = kbase + e;
        f[e] = (k < 73) ? crow[k] : (k == 73 ? 1.f : 0.f);
      }
      f16x8 af = packA(f);
      zac[0] = mf(af, wa[t * 2 + 0], zac[0]);
      zac[1] = mf(af, wa[t * 2 + 1], zac[1]);
    }
    // D rows: row=4*lq+reg -> b = r0+4g+lq, c = reg; softmax lane-local
#pragma unroll
    for (int f = 0; f < 2; ++f) {
      const int j = lm + 16 * f;
      float e0 = __expf(zac[f][0]);
      float e1 = __expf(zac[f][1]);
      float e2 = __expf(zac[f][2]);
      float e3 = __expf(zac[f][3]);
      float den = (e0 + e1) + (e2 + e3);
      float num = fmaf(mr[0 * 2 + f], e0,
                  fmaf(mr[1 * 2 + f], e1,
                  fmaf(mr[2 * 2 + f], e2, mr[3 * 2 + f] * e3)));
      float mg = num * __builtin_amdgcn_rcpf(den);
      ht[(4 * g + lq) * HT_LD + 64 + j] = (__fp16)fast_tanh(mg);
    }
  }

  // ============ fc1: cat(x,u,1) [16x96] @ W1T ============
  f32x4 hac[4] = {{0.f,0.f,0.f,0.f},{0.f,0.f,0.f,0.f},{0.f,0.f,0.f,0.f},{0.f,0.f,0.f,0.f}};
  {
    f16x8 a0 = packA2(xva, xvb);
    f16x8 a1 = packA2(xvc, xvd);
#pragma unroll
    for (int fi = 0; fi < 4; ++fi) hac[fi] = mf(a0, ldB(FC1_OFF + fi * 512), hac[fi]);
#pragma unroll
    for (int fi = 0; fi < 4; ++fi) hac[fi] = mf(a1, ldB(FC1_OFF + (4 + fi) * 512), hac[fi]);
    // t = 2: k = 64..95 -> u part (lq 0,1) + bias-one (k==80) + zeros
    float f[8];
    float uf[8] = {uva.x, uva.y, uva.z, uva.w, uvb.x, uvb.y, uvb.z, uvb.w};
#pragma unroll
    for (int e = 0; e < 8; ++e) {
      int k = 64 + lq * 8 + e;
      f[e] = (k < 80) ? ((lq < 2) ? uf[e] : 0.f) : (k == 80 ? 1.f : 0.f);
    }
    f16x8 a2f = packA(f);
#pragma unroll
    for (int fi = 0; fi < 4; ++fi) hac[fi] = mf(a2f, ldB(FC1_OFF + (8 + fi) * 512), hac[fi]);
  }
  // L2 normalize rows of h1, tanh, stash to ht cols 0..63
  {
    float rn[4];
#pragma unroll
    for (int reg = 0; reg < 4; ++reg) {
      float s = hac[0][reg] * hac[0][reg];
      s = fmaf(hac[1][reg], hac[1][reg], s);
      s = fmaf(hac[2][reg], hac[2][reg], s);
      s = fmaf(hac[3][reg], hac[3][reg], s);
      s += __shfl_xor(s, 1);
      s += __shfl_xor(s, 2);
      s += __shfl_xor(s, 4);
      s += __shfl_xor(s, 8);
      rn[reg] = __builtin_amdgcn_rcpf(fmaxf(sqrtf(s), 1e-12f));
    }
#pragma unroll
    for (int fi = 0; fi < 4; ++fi)
#pragma unroll
      for (int reg = 0; reg < 4; ++reg)
        ht[(4 * lq + reg) * HT_LD + lm + 16 * fi] =
            (__fp16)fast_tanh(hac[fi][reg] * rn[reg]);
  }

  // ============ fc2: [16x96] @ W2T + b2, tanh ============
  {
    f32x4 ac2[4] = {{0.f,0.f,0.f,0.f},{0.f,0.f,0.f,0.f},{0.f,0.f,0.f,0.f},{0.f,0.f,0.f,0.f}};
    f16x8 a2[3];
#pragma unroll
    for (int t = 0; t < 3; ++t)
      a2[t] = *reinterpret_cast<const f16x8*>(ht + lm * HT_LD + t * 32 + lq * 8);
#pragma unroll
    for (int t = 0; t < 3; ++t)
#pragma unroll
      for (int fi = 0; fi < 4; ++fi)
        ac2[fi] = mf(a2[t], ldB(FC2_OFF + (t * 4 + fi) * 512), ac2[fi]);
    // h2t aliases csw — attention reads are complete (DS in-order per wave)
#pragma unroll
    for (int fi = 0; fi < 4; ++fi) {
      float bv = b2[lm + 16 * fi];
#pragma unroll
      for (int reg = 0; reg < 4; ++reg)
        h2t[(4 * lq + reg) * H2_LD + lm + 16 * fi] =
            (__fp16)fast_tanh(ac2[fi][reg] + bv);
    }
  }

  // ============ fc3: [16x64] @ W3T + b3, L2 norm, store ============
  {
    f32x4 o[2] = {{0.f,0.f,0.f,0.f},{0.f,0.f,0.f,0.f}};
    f16x8 a3[2];
#pragma unroll
    for (int t = 0; t < 2; ++t)
      a3[t] = *reinterpret_cast<const f16x8*>(h2t + lm * H2_LD + t * 32 + lq * 8);
#pragma unroll
    for (int t = 0; t < 2; ++t)
#pragma unroll
      for (int fi = 0; fi < 2; ++fi)
        o[fi] = mf(a3[t], ldB(FC3_OFF + (t * 2 + fi) * 512), o[fi]);
#pragma unroll
    for (int fi = 0; fi < 2; ++fi) {
      float bv = b3[lm + 16 * fi];
#pragma unroll
      for (int reg = 0; reg < 4; ++reg) o[fi][reg] += bv;
    }
    float rn2[4];
#pragma unroll
    for (int reg = 0; reg < 4; ++reg) {
      float s = fmaf(o[0][reg], o[0][reg], o[1][reg] * o[1][reg]);
      s += __shfl_xor(s, 1);
      s += __shfl_xor(s, 2);
      s += __shfl_xor(s, 4);
      s += __shfl_xor(s, 8);
      rn2[reg] = __builtin_amdgcn_rcpf(fmaxf(sqrtf(s), 1e-12f));
    }
#pragma unroll
    for (int fi = 0; fi < 2; ++fi)
#pragma unroll
      for (int reg = 0; reg < 4; ++reg)
        out[(size_t)(r0 + 4 * lq + reg) * MSG + lm + 16 * fi] =
            o[fi][reg] * rn2[reg];
  }
}

extern "C" void kernel_launch(void* const* d_in, const int* in_sizes, int n_in,
                              void* d_out, int out_size, void* d_ws, size_t ws_size,
                              hipStream_t stream) {
  const float* x  = (const float*)d_in[0];
  const float* u  = (const float*)d_in[1];
  const float* cs = (const float*)d_in[2];
  const float* m  = (const float*)d_in[3];
  const float* W1 = (const float*)d_in[4];
  const float* b1 = (const float*)d_in[5];
  const float* W2 = (const float*)d_in[6];
  const float* b2 = (const float*)d_in[7];
  const float* W3 = (const float*)d_in[8];
  const float* b3 = (const float*)d_in[9];
  const float* Wa = (const float*)d_in[10];
  const float* ba = (const float*)d_in[11];
  float* out = (float*)d_out;
  ushort* wsf = (ushort*)d_ws;

  const int n = in_sizes[0] / S;  // batch rows

  hipLaunchKernelGGL(prep_pack, dim3((WS_ELEMS + 255) / 256), dim3(256), 0, stream,
                     W1, b1, Wa, ba, W2, W3, wsf);

  const int blocks = (n + 63) / 64;  // 64 rows per block (4 waves x 16)
  hipLaunchKernelGGL(critic_mfma_kernel, dim3(blocks), dim3(256), 0, stream,
                     x, u, cs, m, b2, b3, wsf, out, n);
}